// Round 1
// baseline (314.148 us; speedup 1.0000x reference)
//
#include <hip/hip_runtime.h>
#include <math.h>

#define BB 2
#define NN 1024
#define CC 256
#define NQ 100
#define HALF 128

__device__ __forceinline__ float gelu_exact(float x) {
    return 0.5f * x * (1.0f + erff(x * 0.70710678118654752f));
}

// ---------------- K1: h = gelu(LN(x) @ W_in + b_in), 4 rows/block ----------------
__global__ __launch_bounds__(256) void k1_ln_gemm(
        const float* __restrict__ x, const float* __restrict__ ln_g,
        const float* __restrict__ ln_b, const float* __restrict__ W_in,
        const float* __restrict__ b_in, float* __restrict__ h) {
    __shared__ float xs[4][CC];
    int t = threadIdx.x;
    int wave = t >> 6, lane = t & 63;
    int row0 = blockIdx.x * 4;
    const float* xr = x + (size_t)(row0 + wave) * CC;
    float v0 = xr[lane], v1 = xr[lane + 64], v2 = xr[lane + 128], v3 = xr[lane + 192];
    float s = v0 + v1 + v2 + v3;
    for (int off = 32; off; off >>= 1) s += __shfl_down(s, off);
    s = __shfl(s, 0);
    float mu = s * (1.0f / CC);
    float d0 = v0 - mu, d1 = v1 - mu, d2 = v2 - mu, d3 = v3 - mu;
    float vs = d0 * d0 + d1 * d1 + d2 * d2 + d3 * d3;
    for (int off = 32; off; off >>= 1) vs += __shfl_down(vs, off);
    vs = __shfl(vs, 0);
    float rstd = rsqrtf(vs * (1.0f / CC) + 1e-5f);
    xs[wave][lane]       = d0 * rstd * ln_g[lane]       + ln_b[lane];
    xs[wave][lane + 64]  = d1 * rstd * ln_g[lane + 64]  + ln_b[lane + 64];
    xs[wave][lane + 128] = d2 * rstd * ln_g[lane + 128] + ln_b[lane + 128];
    xs[wave][lane + 192] = d3 * rstd * ln_g[lane + 192] + ln_b[lane + 192];
    __syncthreads();
    float a0 = b_in[t], a1 = a0, a2 = a0, a3 = a0;
    for (int k = 0; k < CC; ++k) {
        float w = W_in[k * CC + t];
        a0 += xs[0][k] * w; a1 += xs[1][k] * w;
        a2 += xs[2][k] * w; a3 += xs[3][k] * w;
    }
    h[(size_t)(row0 + 0) * CC + t] = gelu_exact(a0);
    h[(size_t)(row0 + 1) * CC + t] = gelu_exact(a1);
    h[(size_t)(row0 + 2) * CC + t] = gelu_exact(a2);
    h[(size_t)(row0 + 3) * CC + t] = gelu_exact(a3);
}

// ---------------- K2a: partial glob sums over j-chunks ----------------
__global__ __launch_bounds__(128) void k2a_globpart(
        const float* __restrict__ h, const float* __restrict__ policy,
        float* __restrict__ gpart, float* __restrict__ ppart) {
    int b = blockIdx.x >> 3, chunk = blockIdx.x & 7;
    int c = threadIdx.x;  // 0..127
    int j0 = chunk * 128;
    float acc = 0.f, psum = 0.f;
    for (int j = j0; j < j0 + 128; ++j) {
        float p = policy[b * NN + j];
        acc += h[(size_t)(b * NN + j) * CC + HALF + c] * p;
        psum += p;
    }
    gpart[(b * 8 + chunk) * 128 + c] = acc;
    if (c == 0) ppart[b * 8 + chunk] = psum;
}

// ---------------- K2b: glob = Σ/Σp, then Gterm[b] = glob@W1[128:256] + b1 ----------------
__global__ __launch_bounds__(256) void k2b_gterm(
        const float* __restrict__ gpart, const float* __restrict__ ppart,
        const float* __restrict__ W1, const float* __restrict__ b1,
        float* __restrict__ Gterm) {
    __shared__ float gl[HALF];
    int b = blockIdx.x, t = threadIdx.x;
    if (t < HALF) {
        float s = 0.f, ps = 0.f;
        for (int ch = 0; ch < 8; ++ch) { s += gpart[(b * 8 + ch) * 128 + t]; ps += ppart[b * 8 + ch]; }
        gl[t] = s / ps;
    }
    __syncthreads();
    float acc = b1[t];
    for (int k = 0; k < HALF; ++k) acc += gl[k] * W1[(HALF + k) * CC + t];
    Gterm[b * CC + t] = acc;
}

// ---------------- K3: A'[row] = h_local[row]@W1[0:128] + Gterm[b], 4 rows/block ----------------
__global__ __launch_bounds__(256) void k3_aprime(
        const float* __restrict__ h, const float* __restrict__ W1,
        const float* __restrict__ Gterm, float* __restrict__ A) {
    __shared__ float hs[4][HALF];
    int t = threadIdx.x;
    int row0 = blockIdx.x * 4;
    int b = row0 / NN;
    for (int e = 0; e < 2; ++e) {
        int u = t + e * 256;
        int r = u >> 7, k = u & 127;
        hs[r][k] = h[(size_t)(row0 + r) * CC + k];
    }
    __syncthreads();
    float g = Gterm[b * CC + t];
    float a0 = 0, a1 = 0, a2 = 0, a3 = 0;
    for (int k = 0; k < HALF; ++k) {
        float w = W1[k * CC + t];
        a0 += hs[0][k] * w; a1 += hs[1][k] * w;
        a2 += hs[2][k] * w; a3 += hs[3][k] * w;
    }
    A[(size_t)(row0 + 0) * CC + t] = a0 + g;
    A[(size_t)(row0 + 1) * CC + t] = a1 + g;
    A[(size_t)(row0 + 2) * CC + t] = a2 + g;
    A[(size_t)(row0 + 3) * CC + t] = a3 + g;
}

// ---------------- K4: Qc[b,i] = q[b,i]@W1[256:512] ----------------
__global__ __launch_bounds__(256) void k4_qc(
        const float* __restrict__ query, const float* __restrict__ W1,
        float* __restrict__ Qc) {
    __shared__ float qs[CC];
    int t = threadIdx.x;
    int b = blockIdx.x / NQ, i = blockIdx.x % NQ;
    qs[t] = query[(size_t)(i * BB + b) * CC + t];
    __syncthreads();
    float acc = 0.f;
    for (int k = 0; k < CC; ++k) acc += qs[k] * W1[(2 * HALF + k) * CC + t];
    Qc[(size_t)(b * NQ + i) * CC + t] = acc;
}

// ---------------- K5: fused z1=gelu(A'+Qc); z2=gelu(z1@W2+b2); out=log_softmax(z2@W3+b3) ----
#define MT 64
#define KT 32
#define Z1S 68   // padded k-major stride: 16B-aligned float4 rows, ≤4-way write conflicts

__global__ __launch_bounds__(256) void k5_main(
        const float* __restrict__ A, const float* __restrict__ Qc,
        const float* __restrict__ W2, const float* __restrict__ b2,
        const float* __restrict__ W3, const float* __restrict__ b3,
        float* __restrict__ out) {
    __shared__ float w2s[KT * 128];      // 16 KB
    __shared__ float z1s[KT * Z1S];      // 8.5 KB, layout [k][r]
    __shared__ float part[MT * 33];      // 8.25 KB, padded stride 33

    int t = threadIdx.x;
    int tx = t & 15, ty = t >> 4;
    int blk = blockIdx.x;
    int jt = blk & 15;
    int iq = (blk >> 4) % NQ;
    int b  = blk / (16 * NQ);
    const float* Arow = A + (size_t)(b * NN + jt * MT) * CC;
    const float* Qrow = Qc + (size_t)(b * NQ + iq) * CC;

    float accv[4][8];
    #pragma unroll
    for (int r = 0; r < 4; ++r)
        #pragma unroll
        for (int c = 0; c < 8; ++c) accv[r][c] = 0.f;

    for (int kt = 0; kt < 8; ++kt) {
        int k0 = kt * KT;
        __syncthreads();
        // stage W2[k0:k0+32, :] -> w2s (coalesced float4)
        {
            const float4* W24 = (const float4*)(W2 + k0 * 128);
            float4* w2s4 = (float4*)w2s;
            #pragma unroll
            for (int e = 0; e < 4; ++e) w2s4[t + 256 * e] = W24[t + 256 * e];
        }
        // compute z1 tile -> z1s[k][r] (transposed store)
        #pragma unroll
        for (int e = 0; e < 2; ++e) {
            int u = t + 256 * e;            // float4 unit over (r,kk)
            int r = u >> 3, kk = (u & 7) << 2;
            float4 a4 = *(const float4*)(Arow + r * CC + k0 + kk);
            float4 q4 = *(const float4*)(Qrow + k0 + kk);
            z1s[(kk + 0) * Z1S + r] = gelu_exact(a4.x + q4.x);
            z1s[(kk + 1) * Z1S + r] = gelu_exact(a4.y + q4.y);
            z1s[(kk + 2) * Z1S + r] = gelu_exact(a4.z + q4.z);
            z1s[(kk + 3) * Z1S + r] = gelu_exact(a4.w + q4.w);
        }
        __syncthreads();
        #pragma unroll
        for (int k = 0; k < KT; ++k) {
            float4 av  = *(const float4*)&z1s[k * Z1S + ty * 4];
            float4 bv0 = *(const float4*)&w2s[k * 128 + tx * 4];
            float4 bv1 = *(const float4*)&w2s[k * 128 + 64 + tx * 4];
            float a_[4] = {av.x, av.y, av.z, av.w};
            float b_[8] = {bv0.x, bv0.y, bv0.z, bv0.w, bv1.x, bv1.y, bv1.z, bv1.w};
            #pragma unroll
            for (int rr = 0; rr < 4; ++rr)
                #pragma unroll
                for (int cc = 0; cc < 8; ++cc) accv[rr][cc] += a_[rr] * b_[cc];
        }
    }

    // epilogue: gelu(z2), W3 partials
    float p0[4] = {0, 0, 0, 0}, p1[4] = {0, 0, 0, 0};
    #pragma unroll
    for (int cc = 0; cc < 8; ++cc) {
        int c = (cc < 4) ? (tx * 4 + cc) : (64 + tx * 4 + cc - 4);
        float bb = b2[c];
        float w30 = W3[c * 2 + 0], w31 = W3[c * 2 + 1];
        #pragma unroll
        for (int rr = 0; rr < 4; ++rr) {
            float z = gelu_exact(accv[rr][cc] + bb);
            p0[rr] += z * w30;
            p1[rr] += z * w31;
        }
    }
    #pragma unroll
    for (int rr = 0; rr < 4; ++rr) {
        part[(ty * 4 + rr) * 33 + tx * 2 + 0] = p0[rr];
        part[(ty * 4 + rr) * 33 + tx * 2 + 1] = p1[rr];
    }
    __syncthreads();
    if (t < MT) {
        float z0 = b3[0], z1v = b3[1];
        for (int xx = 0; xx < 16; ++xx) {
            z0  += part[t * 33 + xx * 2 + 0];
            z1v += part[t * 33 + xx * 2 + 1];
        }
        float m = fmaxf(z0, z1v);
        float lse = m + logf(expf(z0 - m) + expf(z1v - m));
        int j = jt * MT + t;
        float2 o = make_float2(z0 - lse, z1v - lse);
        *(float2*)(out + ((size_t)(b * NQ + iq) * NN + j) * 2) = o;
    }
}

extern "C" void kernel_launch(void* const* d_in, const int* in_sizes, int n_in,
                              void* d_out, int out_size, void* d_ws, size_t ws_size,
                              hipStream_t stream) {
    const float* x      = (const float*)d_in[0];
    const float* query  = (const float*)d_in[1];
    const float* policy = (const float*)d_in[2];
    const float* ln_g   = (const float*)d_in[3];
    const float* ln_b   = (const float*)d_in[4];
    const float* W_in   = (const float*)d_in[5];
    const float* b_in   = (const float*)d_in[6];
    const float* W1     = (const float*)d_in[7];
    const float* b1     = (const float*)d_in[8];
    const float* W2     = (const float*)d_in[9];
    const float* b2     = (const float*)d_in[10];
    const float* W3     = (const float*)d_in[11];
    const float* b3     = (const float*)d_in[12];
    float* out = (float*)d_out;

    float* ws    = (float*)d_ws;
    float* h     = ws;                 // 2048*256
    float* A     = ws + 524288;        // 2048*256
    float* Qc    = ws + 1048576;       // 200*256
    float* Gterm = ws + 1099776;       // 2*256
    float* gpart = ws + 1100288;       // 16*128
    float* ppart = ws + 1102336;       // 16

    k1_ln_gemm<<<(BB * NN) / 4, 256, 0, stream>>>(x, ln_g, ln_b, W_in, b_in, h);
    k2a_globpart<<<BB * 8, 128, 0, stream>>>(h, policy, gpart, ppart);
    k2b_gterm<<<BB, 256, 0, stream>>>(gpart, ppart, W1, b1, Gterm);
    k3_aprime<<<(BB * NN) / 4, 256, 0, stream>>>(h, W1, Gterm, A);
    k4_qc<<<BB * NQ, 256, 0, stream>>>(query, W1, Qc);
    k5_main<<<BB * NQ * (NN / MT), 256, 0, stream>>>(A, Qc, W2, b2, W3, b3, out);
}

// Round 2
// 197.814 us; speedup vs baseline: 1.5881x; 1.5881x over previous
//
#include <hip/hip_runtime.h>
#include <math.h>

#define BB 2
#define NN 1024
#define CC 256
#define NQ 100
#define HALF 128

typedef __attribute__((ext_vector_type(8))) short bf16x8;
typedef __attribute__((ext_vector_type(4))) float f32x4;

// Branch-free erf-based gelu (A&S 7.1.26, abs err ~1.5e-7 — far below bf16 rounding)
__device__ __forceinline__ float gelu_fast(float x) {
    float y = 0.70710678118654752f * x;
    float a = fabsf(y);
    float t = __builtin_amdgcn_rcpf(fmaf(0.3275911f, a, 1.0f));
    float p = fmaf(fmaf(fmaf(fmaf(1.061405429f, t, -1.453152027f), t,
                             1.421413741f), t, -0.284496736f), t, 0.254829592f);
    p = p * t;
    float e = __expf(-y * y);
    float erfa = fmaf(-p, e, 1.0f);
    float er = copysignf(erfa, y);
    return 0.5f * x * (1.0f + er);
}

// fp32 -> bf16 RNE
__device__ __forceinline__ short f2bf(float f) {
    union { float f; unsigned u; } v; v.f = f;
    return (short)((v.u + 0x7FFFu + ((v.u >> 16) & 1u)) >> 16);
}

// ---------------- K1: h = gelu(LN(x) @ W_in + b_in), 4 rows/block ----------------
__global__ __launch_bounds__(256) void k1_ln_gemm(
        const float* __restrict__ x, const float* __restrict__ ln_g,
        const float* __restrict__ ln_b, const float* __restrict__ W_in,
        const float* __restrict__ b_in, float* __restrict__ h) {
    __shared__ float xs[4][CC];
    int t = threadIdx.x;
    int wave = t >> 6, lane = t & 63;
    int row0 = blockIdx.x * 4;
    const float* xr = x + (size_t)(row0 + wave) * CC;
    float v0 = xr[lane], v1 = xr[lane + 64], v2 = xr[lane + 128], v3 = xr[lane + 192];
    float s = v0 + v1 + v2 + v3;
    for (int off = 32; off; off >>= 1) s += __shfl_down(s, off);
    s = __shfl(s, 0);
    float mu = s * (1.0f / CC);
    float d0 = v0 - mu, d1 = v1 - mu, d2 = v2 - mu, d3 = v3 - mu;
    float vs = d0 * d0 + d1 * d1 + d2 * d2 + d3 * d3;
    for (int off = 32; off; off >>= 1) vs += __shfl_down(vs, off);
    vs = __shfl(vs, 0);
    float rstd = rsqrtf(vs * (1.0f / CC) + 1e-5f);
    xs[wave][lane]       = d0 * rstd * ln_g[lane]       + ln_b[lane];
    xs[wave][lane + 64]  = d1 * rstd * ln_g[lane + 64]  + ln_b[lane + 64];
    xs[wave][lane + 128] = d2 * rstd * ln_g[lane + 128] + ln_b[lane + 128];
    xs[wave][lane + 192] = d3 * rstd * ln_g[lane + 192] + ln_b[lane + 192];
    __syncthreads();
    float a0 = b_in[t], a1 = a0, a2 = a0, a3 = a0;
    #pragma unroll 8
    for (int k = 0; k < CC; ++k) {
        float w = W_in[k * CC + t];
        a0 += xs[0][k] * w; a1 += xs[1][k] * w;
        a2 += xs[2][k] * w; a3 += xs[3][k] * w;
    }
    h[(size_t)(row0 + 0) * CC + t] = gelu_fast(a0);
    h[(size_t)(row0 + 1) * CC + t] = gelu_fast(a1);
    h[(size_t)(row0 + 2) * CC + t] = gelu_fast(a2);
    h[(size_t)(row0 + 3) * CC + t] = gelu_fast(a3);
}

// ---------------- K2a: partial glob sums over j-chunks ----------------
__global__ __launch_bounds__(128) void k2a_globpart(
        const float* __restrict__ h, const float* __restrict__ policy,
        float* __restrict__ gpart, float* __restrict__ ppart) {
    int b = blockIdx.x >> 3, chunk = blockIdx.x & 7;
    int c = threadIdx.x;  // 0..127
    int j0 = chunk * 128;
    float acc = 0.f, psum = 0.f;
    #pragma unroll 4
    for (int j = j0; j < j0 + 128; ++j) {
        float p = policy[b * NN + j];
        acc += h[(size_t)(b * NN + j) * CC + HALF + c] * p;
        psum += p;
    }
    gpart[(b * 8 + chunk) * 128 + c] = acc;
    if (c == 0) ppart[b * 8 + chunk] = psum;
}

// ---------------- K2b: glob = sum/sum_p, Gterm[b] = glob@W1[128:256] + b1 ----------------
__global__ __launch_bounds__(256) void k2b_gterm(
        const float* __restrict__ gpart, const float* __restrict__ ppart,
        const float* __restrict__ W1, const float* __restrict__ b1,
        float* __restrict__ Gterm) {
    __shared__ float gl[HALF];
    int b = blockIdx.x, t = threadIdx.x;
    if (t < HALF) {
        float s = 0.f, ps = 0.f;
        for (int ch = 0; ch < 8; ++ch) { s += gpart[(b * 8 + ch) * 128 + t]; ps += ppart[b * 8 + ch]; }
        gl[t] = s / ps;
    }
    __syncthreads();
    float acc = b1[t];
    #pragma unroll 8
    for (int k = 0; k < HALF; ++k) acc += gl[k] * W1[(HALF + k) * CC + t];
    Gterm[b * CC + t] = acc;
}

// ---------------- K3: A'[row] = h_local[row]@W1[0:128] + Gterm[b] ----------------
__global__ __launch_bounds__(256) void k3_aprime(
        const float* __restrict__ h, const float* __restrict__ W1,
        const float* __restrict__ Gterm, float* __restrict__ A) {
    __shared__ float hs[4][HALF];
    int t = threadIdx.x;
    int row0 = blockIdx.x * 4;
    int b = row0 / NN;
    for (int e = 0; e < 2; ++e) {
        int u = t + e * 256;
        int r = u >> 7, k = u & 127;
        hs[r][k] = h[(size_t)(row0 + r) * CC + k];
    }
    __syncthreads();
    float g = Gterm[b * CC + t];
    float a0 = 0, a1 = 0, a2 = 0, a3 = 0;
    #pragma unroll 8
    for (int k = 0; k < HALF; ++k) {
        float w = W1[k * CC + t];
        a0 += hs[0][k] * w; a1 += hs[1][k] * w;
        a2 += hs[2][k] * w; a3 += hs[3][k] * w;
    }
    A[(size_t)(row0 + 0) * CC + t] = a0 + g;
    A[(size_t)(row0 + 1) * CC + t] = a1 + g;
    A[(size_t)(row0 + 2) * CC + t] = a2 + g;
    A[(size_t)(row0 + 3) * CC + t] = a3 + g;
}

// ---------------- K4: Qc[b,i] = q[b,i]@W1[256:512] ----------------
__global__ __launch_bounds__(256) void k4_qc(
        const float* __restrict__ query, const float* __restrict__ W1,
        float* __restrict__ Qc) {
    __shared__ float qs[CC];
    int t = threadIdx.x;
    int b = blockIdx.x / NQ, i = blockIdx.x % NQ;
    qs[t] = query[(size_t)(i * BB + b) * CC + t];
    __syncthreads();
    float acc = 0.f;
    #pragma unroll 8
    for (int k = 0; k < CC; ++k) acc += qs[k] * W1[(2 * HALF + k) * CC + t];
    Qc[(size_t)(b * NQ + i) * CC + t] = acc;
}

// ---------------- Kprep: W2 fp32 [256][128] -> W2T bf16 [c=128][k=256] ----------------
__global__ __launch_bounds__(256) void kprep_w2(
        const float* __restrict__ W2, short* __restrict__ W2T) {
    int u = blockIdx.x * 256 + threadIdx.x;   // 32 blocks -> 8192 threads, 4 elems each
    int c = u >> 6, kg = u & 63;
    short4 v;
    v.x = f2bf(W2[(kg * 4 + 0) * HALF + c]);
    v.y = f2bf(W2[(kg * 4 + 1) * HALF + c]);
    v.z = f2bf(W2[(kg * 4 + 2) * HALF + c]);
    v.w = f2bf(W2[(kg * 4 + 3) * HALF + c]);
    *(short4*)(W2T + c * CC + kg * 4) = v;
}

// ---------------- K5: z1=gelu(A'+Qc) -> MFMA z1@W2 -> gelu -> W3 -> log_softmax ----
// Block tile: M=128 (j), N=128 (W2 cols), K=256. 4 waves in 2x2, wave-tile 64x64.
// KC=64 K-chunk; z1 computed to LDS bf16, W2 staged from pre-converted bf16.
#define KC 64
#define Z1S 72   // bf16 row stride: 144 B -> 16B-aligned, 2-way banks only (free)

__global__ __launch_bounds__(256) void k5_main(
        const float* __restrict__ A, const float* __restrict__ Qc,
        const short* __restrict__ W2T, const float* __restrict__ b2,
        const float* __restrict__ W3, const float* __restrict__ b3,
        float* __restrict__ out) {
    __shared__ short z1s[128 * Z1S];   // 18432 B
    __shared__ short w2s[128 * Z1S];   // 18432 B
    __shared__ float part[128 * 2 * 2]; // 2048 B

    int t = threadIdx.x;
    int lane = t & 63, w = t >> 6;
    int wr = w & 1, wc = w >> 1;
    int col16 = lane & 15, quad = lane >> 4;
    int blk = blockIdx.x;
    int jt = blk & 7;
    int iq = (blk >> 3) % NQ;
    int b  = blk / (8 * NQ);
    const float* Arow = A + ((size_t)b * NN + jt * 128) * CC;
    const float* Qrow = Qc + (size_t)(b * NQ + iq) * CC;

    f32x4 acc[4][4];
    #pragma unroll
    for (int mi = 0; mi < 4; ++mi)
        #pragma unroll
        for (int ni = 0; ni < 4; ++ni)
            acc[mi][ni] = (f32x4){0.f, 0.f, 0.f, 0.f};

    for (int kt = 0; kt < 4; ++kt) {
        int k0 = kt * KC;
        __syncthreads();
        // stage z1 tile: 128 rows x 64 k, gelu(A'+Qc) -> bf16
        #pragma unroll
        for (int e = 0; e < 8; ++e) {
            int u = t + 256 * e;
            int row = u >> 4, kq = u & 15;
            float4 a4 = *(const float4*)(Arow + (size_t)row * CC + k0 + kq * 4);
            float4 q4 = *(const float4*)(Qrow + k0 + kq * 4);
            short4 hv;
            hv.x = f2bf(gelu_fast(a4.x + q4.x));
            hv.y = f2bf(gelu_fast(a4.y + q4.y));
            hv.z = f2bf(gelu_fast(a4.z + q4.z));
            hv.w = f2bf(gelu_fast(a4.w + q4.w));
            *(short4*)&z1s[row * Z1S + kq * 4] = hv;
        }
        // stage W2 tile: 128 n x 64 k from pre-converted bf16
        #pragma unroll
        for (int e = 0; e < 4; ++e) {
            int u = t + 256 * e;
            int n = u >> 3, kg = u & 7;
            *(bf16x8*)&w2s[n * Z1S + kg * 8] =
                *(const bf16x8*)(W2T + n * CC + k0 + kg * 8);
        }
        __syncthreads();
        #pragma unroll
        for (int s = 0; s < 2; ++s) {
            int koff = s * 32 + quad * 8;
            bf16x8 af[4], bfr[4];
            #pragma unroll
            for (int mi = 0; mi < 4; ++mi)
                af[mi] = *(const bf16x8*)&z1s[(wr * 64 + mi * 16 + col16) * Z1S + koff];
            #pragma unroll
            for (int ni = 0; ni < 4; ++ni)
                bfr[ni] = *(const bf16x8*)&w2s[(wc * 64 + ni * 16 + col16) * Z1S + koff];
            #pragma unroll
            for (int mi = 0; mi < 4; ++mi)
                #pragma unroll
                for (int ni = 0; ni < 4; ++ni)
                    acc[mi][ni] = __builtin_amdgcn_mfma_f32_16x16x32_bf16(
                        af[mi], bfr[ni], acc[mi][ni], 0, 0, 0);
        }
    }

    // epilogue: z2 = gelu(acc + b2), partials vs W3, reduce over cols
    float p0[4][4], p1[4][4];
    #pragma unroll
    for (int mi = 0; mi < 4; ++mi)
        #pragma unroll
        for (int r = 0; r < 4; ++r) { p0[mi][r] = 0.f; p1[mi][r] = 0.f; }

    #pragma unroll
    for (int ni = 0; ni < 4; ++ni) {
        int c = wc * 64 + ni * 16 + col16;
        float bb = b2[c];
        float2 w3v = *(const float2*)(W3 + c * 2);
        #pragma unroll
        for (int mi = 0; mi < 4; ++mi)
            #pragma unroll
            for (int r = 0; r < 4; ++r) {
                float z = gelu_fast(acc[mi][ni][r] + bb);
                p0[mi][r] = fmaf(z, w3v.x, p0[mi][r]);
                p1[mi][r] = fmaf(z, w3v.y, p1[mi][r]);
            }
    }
    #pragma unroll
    for (int mi = 0; mi < 4; ++mi)
        #pragma unroll
        for (int r = 0; r < 4; ++r) {
            float s0 = p0[mi][r], s1 = p1[mi][r];
            #pragma unroll
            for (int off = 1; off < 16; off <<= 1) {
                s0 += __shfl_xor(s0, off);
                s1 += __shfl_xor(s1, off);
            }
            if (col16 == 0) {
                int row = wr * 64 + mi * 16 + quad * 4 + r;
                *(float2*)&part[(row * 2 + wc) * 2] = make_float2(s0, s1);
            }
        }
    __syncthreads();
    if (t < 128) {
        float a0 = part[(t * 2 + 0) * 2 + 0], a1 = part[(t * 2 + 0) * 2 + 1];
        float c0 = part[(t * 2 + 1) * 2 + 0], c1 = part[(t * 2 + 1) * 2 + 1];
        float z0 = b3[0] + a0 + c0;
        float z1v = b3[1] + a1 + c1;
        float m = fmaxf(z0, z1v);
        float lse = m + logf(__expf(z0 - m) + __expf(z1v - m));
        int j = jt * 128 + t;
        *(float2*)(out + ((size_t)(b * NQ + iq) * NN + j) * 2) =
            make_float2(z0 - lse, z1v - lse);
    }
}

extern "C" void kernel_launch(void* const* d_in, const int* in_sizes, int n_in,
                              void* d_out, int out_size, void* d_ws, size_t ws_size,
                              hipStream_t stream) {
    const float* x      = (const float*)d_in[0];
    const float* query  = (const float*)d_in[1];
    const float* policy = (const float*)d_in[2];
    const float* ln_g   = (const float*)d_in[3];
    const float* ln_b   = (const float*)d_in[4];
    const float* W_in   = (const float*)d_in[5];
    const float* b_in   = (const float*)d_in[6];
    const float* W1     = (const float*)d_in[7];
    const float* b1     = (const float*)d_in[8];
    const float* W2     = (const float*)d_in[9];
    const float* b2     = (const float*)d_in[10];
    const float* W3     = (const float*)d_in[11];
    const float* b3     = (const float*)d_in[12];
    float* out = (float*)d_out;

    float* ws    = (float*)d_ws;
    float* h     = ws;                 // 2048*256 fp32 (dead after k3; W2T overlays)
    float* A     = ws + 524288;        // 2048*256
    float* Qc    = ws + 1048576;       // 200*256
    float* Gterm = ws + 1099776;       // 2*256
    float* gpart = ws + 1100288;       // 16*128
    float* ppart = ws + 1102336;       // 16
    short* W2T   = (short*)ws;         // 128*256 bf16 = 64 KB, overlays h after k3

    k1_ln_gemm<<<(BB * NN) / 4, 256, 0, stream>>>(x, ln_g, ln_b, W_in, b_in, h);
    k2a_globpart<<<BB * 8, 128, 0, stream>>>(h, policy, gpart, ppart);
    k2b_gterm<<<BB, 256, 0, stream>>>(gpart, ppart, W1, b1, Gterm);
    k3_aprime<<<(BB * NN) / 4, 256, 0, stream>>>(h, W1, Gterm, A);
    kprep_w2<<<32, 256, 0, stream>>>(W2, W2T);   // after k3: h region is dead
    k4_qc<<<BB * NQ, 256, 0, stream>>>(query, W1, Qc);
    k5_main<<<BB * NQ * (NN / 128), 256, 0, stream>>>(A, Qc, W2T, b2, W3, b3, out);
}

// Round 3
// 196.558 us; speedup vs baseline: 1.5982x; 1.0064x over previous
//
#include <hip/hip_runtime.h>
#include <math.h>

#define BB 2
#define NN 1024
#define CC 256
#define NQ 100
#define HALF 128

typedef __attribute__((ext_vector_type(8))) short bf16x8;
typedef __attribute__((ext_vector_type(4))) float f32x4;

// gelu via A&S 7.1.28 erf: 1 - (1+a1 x+...+a6 x^6)^-16, |err| <= 3e-7.
// One v_rcp (trans), zero exp. Large |x| -> p^16 -> inf -> rcp -> 0 (correct).
__device__ __forceinline__ float gelu_fast(float x) {
    float a = fabsf(0.70710678118654752f * x);
    float t = fmaf(a, 4.30638e-5f, 2.765672e-4f);
    t = fmaf(a, t, 1.520143e-4f);
    t = fmaf(a, t, 9.2705272e-3f);
    t = fmaf(a, t, 4.22820123e-2f);
    t = fmaf(a, t, 7.05230784e-2f);
    float p = fmaf(a, t, 1.0f);
    float p2 = p * p;
    float p4 = p2 * p2;
    float p8 = p4 * p4;
    float p16 = p8 * p8;
    float r = 0.5f * __builtin_amdgcn_rcpf(p16);   // 0.5*(1-erf(a))
    float phi = (x >= 0.0f) ? (1.0f - r) : r;      // Phi(x)
    return x * phi;
}

// fp32 -> bf16 RNE
__device__ __forceinline__ short f2bf(float f) {
    union { float f; unsigned u; } v; v.f = f;
    return (short)((v.u + 0x7FFFu + ((v.u >> 16) & 1u)) >> 16);
}

// ---- K1: h = gelu(LN(x)@W_in + b_in); fused glob partial sums (atomics) ----
// LDS layout [k][row4] -> one uniform-address ds_read_b128 per K-iter (broadcast).
__global__ __launch_bounds__(256) void k1_ln_gemm(
        const float* __restrict__ x, const float* __restrict__ ln_g,
        const float* __restrict__ ln_b, const float* __restrict__ W_in,
        const float* __restrict__ b_in, const float* __restrict__ policy,
        float* __restrict__ h, float* __restrict__ gsum, float* __restrict__ psum) {
    __shared__ float xst[CC][4];
    int t = threadIdx.x;
    int wave = t >> 6, lane = t & 63;
    int row0 = blockIdx.x * 4;
    const float* xr = x + (size_t)(row0 + wave) * CC;
    float v0 = xr[lane], v1 = xr[lane + 64], v2 = xr[lane + 128], v3 = xr[lane + 192];
    float s = v0 + v1 + v2 + v3;
    for (int off = 32; off; off >>= 1) s += __shfl_down(s, off);
    s = __shfl(s, 0);
    float mu = s * (1.0f / CC);
    float d0 = v0 - mu, d1 = v1 - mu, d2 = v2 - mu, d3 = v3 - mu;
    float vs = d0 * d0 + d1 * d1 + d2 * d2 + d3 * d3;
    for (int off = 32; off; off >>= 1) vs += __shfl_down(vs, off);
    vs = __shfl(vs, 0);
    float rstd = rsqrtf(vs * (1.0f / CC) + 1e-5f);
    xst[lane][wave]       = d0 * rstd * ln_g[lane]       + ln_b[lane];
    xst[lane + 64][wave]  = d1 * rstd * ln_g[lane + 64]  + ln_b[lane + 64];
    xst[lane + 128][wave] = d2 * rstd * ln_g[lane + 128] + ln_b[lane + 128];
    xst[lane + 192][wave] = d3 * rstd * ln_g[lane + 192] + ln_b[lane + 192];
    __syncthreads();
    float a0 = b_in[t], a1 = a0, a2 = a0, a3 = a0;
    #pragma unroll 8
    for (int k = 0; k < CC; ++k) {
        float4 xv = *(const float4*)xst[k];     // uniform addr -> broadcast
        float wv = W_in[k * CC + t];
        a0 = fmaf(xv.x, wv, a0); a1 = fmaf(xv.y, wv, a1);
        a2 = fmaf(xv.z, wv, a2); a3 = fmaf(xv.w, wv, a3);
    }
    float h0 = gelu_fast(a0), h1 = gelu_fast(a1), h2 = gelu_fast(a2), h3 = gelu_fast(a3);
    h[(size_t)(row0 + 0) * CC + t] = h0;
    h[(size_t)(row0 + 1) * CC + t] = h1;
    h[(size_t)(row0 + 2) * CC + t] = h2;
    h[(size_t)(row0 + 3) * CC + t] = h3;
    float p0 = policy[row0], p1 = policy[row0 + 1], p2 = policy[row0 + 2], p3 = policy[row0 + 3];
    int b = row0 >> 10;
    if (t >= HALF) {
        float wsum = h0 * p0 + h1 * p1 + h2 * p2 + h3 * p3;
        atomicAdd(&gsum[b * HALF + (t - HALF)], wsum);
    }
    if (t == 0) atomicAdd(&psum[b], p0 + p1 + p2 + p3);
}

// ---- K2b: glob = gsum/psum, Gterm[b] = glob@W1[128:256] + b1 ----
__global__ __launch_bounds__(256) void k2b_gterm(
        const float* __restrict__ gsum, const float* __restrict__ psum,
        const float* __restrict__ W1, const float* __restrict__ b1,
        float* __restrict__ Gterm) {
    __shared__ float gl[HALF];
    int b = blockIdx.x, t = threadIdx.x;
    if (t < HALF) gl[t] = gsum[b * HALF + t] / psum[b];
    __syncthreads();
    float acc = b1[t];
    #pragma unroll 8
    for (int k = 0; k < HALF; ++k) acc = fmaf(gl[k], W1[(HALF + k) * CC + t], acc);
    Gterm[b * CC + t] = acc;
}

// ---- K3: A[row] = h_local[row]@W1[0:128] + Gterm[b]; [k][row4] broadcast layout ----
__global__ __launch_bounds__(256) void k3_aprime(
        const float* __restrict__ h, const float* __restrict__ W1,
        const float* __restrict__ Gterm, float* __restrict__ A) {
    __shared__ float hst[HALF][4];
    int t = threadIdx.x;
    int row0 = blockIdx.x * 4;
    int b = row0 >> 10;
    #pragma unroll
    for (int e = 0; e < 2; ++e) {
        int u = e * 256 + t;
        int r = u >> 7, k = u & 127;
        hst[k][r] = h[(size_t)(row0 + r) * CC + k];
    }
    __syncthreads();
    float g = Gterm[b * CC + t];
    float a0 = 0, a1 = 0, a2 = 0, a3 = 0;
    #pragma unroll 8
    for (int k = 0; k < HALF; ++k) {
        float4 hv = *(const float4*)hst[k];     // uniform addr -> broadcast
        float wv = W1[k * CC + t];
        a0 = fmaf(hv.x, wv, a0); a1 = fmaf(hv.y, wv, a1);
        a2 = fmaf(hv.z, wv, a2); a3 = fmaf(hv.w, wv, a3);
    }
    A[(size_t)(row0 + 0) * CC + t] = a0 + g;
    A[(size_t)(row0 + 1) * CC + t] = a1 + g;
    A[(size_t)(row0 + 2) * CC + t] = a2 + g;
    A[(size_t)(row0 + 3) * CC + t] = a3 + g;
}

// ---- K4: Qc[b,i] = q[b,i]@W1[256:512]  (+ fused W2 -> bf16 [n][k] transpose) ----
__global__ __launch_bounds__(256) void k4_qc_prep(
        const float* __restrict__ query, const float* __restrict__ W1,
        const float* __restrict__ W2, float* __restrict__ Qc,
        short* __restrict__ W2T) {
    __shared__ float qs[CC];
    int blk = blockIdx.x, t = threadIdx.x;
    if (blk < BB * NQ) {
        int b = blk / NQ, i = blk % NQ;
        qs[t] = query[(size_t)(i * BB + b) * CC + t];
        __syncthreads();
        float acc = 0.f;
        #pragma unroll 8
        for (int k = 0; k < CC; ++k) acc = fmaf(qs[k], W1[(2 * HALF + k) * CC + t], acc);
        Qc[(size_t)blk * CC + t] = acc;
    } else {
        int u = (blk - BB * NQ) * 256 + t;
        int c = u >> 6, kg = u & 63;
        short4 v;
        v.x = f2bf(W2[(kg * 4 + 0) * HALF + c]);
        v.y = f2bf(W2[(kg * 4 + 1) * HALF + c]);
        v.z = f2bf(W2[(kg * 4 + 2) * HALF + c]);
        v.w = f2bf(W2[(kg * 4 + 3) * HALF + c]);
        *(short4*)(W2T + c * CC + kg * 4) = v;
    }
}

// ---- K5: register-direct z1 frags -> MFMA vs LDS-staged W2 -> gelu -> W3 -> lsm ----
// 4 waves, wave-tile m=32 x n=128. A-frag computed in-register (no z1 LDS, no
// per-K barriers). W2 bf16 staged in 2 K-chunks; 3 barriers total per block.
#define W2S 136   // bf16 row stride: 272 B = 17*16 (b128-aligned), 2-way banks (free)

__global__ __launch_bounds__(256, 3) void k5_main(
        const float* __restrict__ A, const float* __restrict__ Qc,
        const short* __restrict__ W2T, const float* __restrict__ b2,
        const float* __restrict__ W3, const float* __restrict__ b3,
        float* __restrict__ out) {
    __shared__ short w2s[128 * W2S];   // 34816 B

    int t = threadIdx.x;
    int lane = t & 63, w = t >> 6;
    int col16 = lane & 15, quad = lane >> 4;
    int blk = blockIdx.x;
    int jt = blk & 7;                  // 8 j-tiles: jt == XCD id -> A-tile L2 locality
    int iq = (blk >> 3) % NQ;
    int b  = blk / (8 * NQ);
    const float* A0 = A + (size_t)(b * NN + jt * 128 + w * 32 + col16) * CC;
    const float* A1 = A0 + 16 * CC;
    const float* Qrow = Qc + (size_t)(b * NQ + iq) * CC;

    f32x4 acc[2][8];
    #pragma unroll
    for (int mi = 0; mi < 2; ++mi)
        #pragma unroll
        for (int ni = 0; ni < 8; ++ni)
            acc[mi][ni] = (f32x4){0.f, 0.f, 0.f, 0.f};

    for (int kt = 0; kt < 2; ++kt) {
        __syncthreads();
        #pragma unroll
        for (int e = 0; e < 8; ++e) {
            int u = e * 256 + t;
            int n = u >> 4, kg = u & 15;
            *(bf16x8*)&w2s[n * W2S + kg * 8] =
                *(const bf16x8*)(W2T + n * CC + kt * 128 + kg * 8);
        }
        __syncthreads();
        #pragma unroll
        for (int ks = 0; ks < 4; ++ks) {
            int k0 = kt * 128 + ks * 32 + quad * 8;
            float4 q0 = *(const float4*)(Qrow + k0);
            float4 q1 = *(const float4*)(Qrow + k0 + 4);
            bf16x8 af[2];
            #pragma unroll
            for (int mi = 0; mi < 2; ++mi) {
                const float* Ap = (mi ? A1 : A0) + k0;
                float4 a0 = *(const float4*)(Ap);
                float4 a1 = *(const float4*)(Ap + 4);
                union { bf16x8 v; short s[8]; } u;
                u.s[0] = f2bf(gelu_fast(a0.x + q0.x));
                u.s[1] = f2bf(gelu_fast(a0.y + q0.y));
                u.s[2] = f2bf(gelu_fast(a0.z + q0.z));
                u.s[3] = f2bf(gelu_fast(a0.w + q0.w));
                u.s[4] = f2bf(gelu_fast(a1.x + q1.x));
                u.s[5] = f2bf(gelu_fast(a1.y + q1.y));
                u.s[6] = f2bf(gelu_fast(a1.z + q1.z));
                u.s[7] = f2bf(gelu_fast(a1.w + q1.w));
                af[mi] = u.v;
            }
            int klocal = ks * 32 + quad * 8;
            #pragma unroll
            for (int ni = 0; ni < 8; ++ni) {
                bf16x8 bfv = *(const bf16x8*)&w2s[(ni * 16 + col16) * W2S + klocal];
                acc[0][ni] = __builtin_amdgcn_mfma_f32_16x16x32_bf16(af[0], bfv, acc[0][ni], 0, 0, 0);
                acc[1][ni] = __builtin_amdgcn_mfma_f32_16x16x32_bf16(af[1], bfv, acc[1][ni], 0, 0, 0);
            }
        }
    }

    // epilogue: z2 = gelu(acc + b2); logits = z2@W3; reduce over col16 lanes; lsm
    float p0[2][4], p1[2][4];
    #pragma unroll
    for (int mi = 0; mi < 2; ++mi)
        #pragma unroll
        for (int r = 0; r < 4; ++r) { p0[mi][r] = 0.f; p1[mi][r] = 0.f; }

    #pragma unroll
    for (int ni = 0; ni < 8; ++ni) {
        int c = ni * 16 + col16;
        float bb = b2[c];
        float2 w3v = *(const float2*)(W3 + c * 2);
        #pragma unroll
        for (int mi = 0; mi < 2; ++mi)
            #pragma unroll
            for (int r = 0; r < 4; ++r) {
                float z = gelu_fast(acc[mi][ni][r] + bb);
                p0[mi][r] = fmaf(z, w3v.x, p0[mi][r]);
                p1[mi][r] = fmaf(z, w3v.y, p1[mi][r]);
            }
    }
    float b30 = b3[0], b31 = b3[1];
    #pragma unroll
    for (int mi = 0; mi < 2; ++mi)
        #pragma unroll
        for (int r = 0; r < 4; ++r) {
            float s0 = p0[mi][r], s1 = p1[mi][r];
            #pragma unroll
            for (int off = 1; off < 16; off <<= 1) {
                s0 += __shfl_xor(s0, off);
                s1 += __shfl_xor(s1, off);
            }
            if (col16 == 0) {
                float z0 = s0 + b30, z1v = s1 + b31;
                float m = fmaxf(z0, z1v);
                float lse = m + __logf(__expf(z0 - m) + __expf(z1v - m));
                int row = w * 32 + mi * 16 + quad * 4 + r;
                int j = jt * 128 + row;
                *(float2*)(out + ((size_t)(b * NQ + iq) * NN + j) * 2) =
                    make_float2(z0 - lse, z1v - lse);
            }
        }
}

extern "C" void kernel_launch(void* const* d_in, const int* in_sizes, int n_in,
                              void* d_out, int out_size, void* d_ws, size_t ws_size,
                              hipStream_t stream) {
    const float* x      = (const float*)d_in[0];
    const float* query  = (const float*)d_in[1];
    const float* policy = (const float*)d_in[2];
    const float* ln_g   = (const float*)d_in[3];
    const float* ln_b   = (const float*)d_in[4];
    const float* W_in   = (const float*)d_in[5];
    const float* b_in   = (const float*)d_in[6];
    const float* W1     = (const float*)d_in[7];
    const float* b1     = (const float*)d_in[8];
    const float* W2     = (const float*)d_in[9];
    const float* b2     = (const float*)d_in[10];
    const float* W3     = (const float*)d_in[11];
    const float* b3     = (const float*)d_in[12];
    float* out = (float*)d_out;

    float* ws    = (float*)d_ws;
    float* h     = ws;                 // 2048*256 fp32 (dead after k3; W2T overlays)
    float* A     = ws + 524288;        // 2048*256
    float* Qc    = ws + 1048576;       // 200*256
    float* Gterm = ws + 1099776;       // 2*256
    float* gsum  = ws + 1100288;       // 2*128
    float* psum  = ws + 1100544;       // 2
    short* W2T   = (short*)ws;         // 128*256 bf16 = 64 KB, overlays h after k3

    hipMemsetAsync(gsum, 0, (2 * HALF + 2) * sizeof(float), stream);
    k1_ln_gemm<<<(BB * NN) / 4, 256, 0, stream>>>(x, ln_g, ln_b, W_in, b_in, policy,
                                                  h, gsum, psum);
    k2b_gterm<<<BB, 256, 0, stream>>>(gsum, psum, W1, b1, Gterm);
    k3_aprime<<<(BB * NN) / 4, 256, 0, stream>>>(h, W1, Gterm, A);
    k4_qc_prep<<<BB * NQ + 32, 256, 0, stream>>>(query, W1, W2, Qc, W2T);
    k5_main<<<BB * NQ * (NN / 128), 256, 0, stream>>>(A, Qc, W2T, b2, W3, b3, out);
}

// Round 4
// 173.866 us; speedup vs baseline: 1.8068x; 1.1305x over previous
//
#include <hip/hip_runtime.h>
#include <math.h>

#define BB 2
#define NN 1024
#define CC 256
#define NQ 100
#define HALF 128

typedef __attribute__((ext_vector_type(8))) short bf16x8;
typedef __attribute__((ext_vector_type(4))) float f32x4;

// gelu via A&S 7.1.28 erf: |err| <= 3e-7 abs; 1 rcp, no exp.
__device__ __forceinline__ float gelu_fast(float x) {
    float a = fabsf(0.70710678118654752f * x);
    float t = fmaf(a, 4.30638e-5f, 2.765672e-4f);
    t = fmaf(a, t, 1.520143e-4f);
    t = fmaf(a, t, 9.2705272e-3f);
    t = fmaf(a, t, 4.22820123e-2f);
    t = fmaf(a, t, 7.05230784e-2f);
    float p = fmaf(a, t, 1.0f);
    float p2 = p * p;
    float p4 = p2 * p2;
    float p8 = p4 * p4;
    float p16 = p8 * p8;
    float r = 0.5f * __builtin_amdgcn_rcpf(p16);   // 0.5*(1-erf(a))
    float phi = (x >= 0.0f) ? (1.0f - r) : r;
    return x * phi;
}

__device__ __forceinline__ short f2bf(float f) {
    union { float f; unsigned u; } v; v.f = f;
    return (short)((v.u + 0x7FFFu + ((v.u >> 16) & 1u)) >> 16);
}

// ---- kA: LN -> W_in GEMM -> gelu (h in regs/LDS only) -> glob atomics
//          -> h_local @ W1[0:128] -> A in MFMA-tiled layout. 4 rows/block. ----
// A tiled layout: At[b][n16=row/16][kq=c/8][r16=row%16][e=c%8], c = 0..255.
__global__ __launch_bounds__(256) void kA_fused(
        const float* __restrict__ x, const float* __restrict__ ln_g,
        const float* __restrict__ ln_b, const float* __restrict__ W_in,
        const float* __restrict__ b_in, const float* __restrict__ policy,
        const float* __restrict__ W1, float* __restrict__ At,
        float* __restrict__ gsum, float* __restrict__ psum) {
    __shared__ float xst[CC][4];
    __shared__ float hst[HALF][4];
    int t = threadIdx.x;
    int wave = t >> 6, lane = t & 63;
    int row0 = blockIdx.x * 4;
    const float* xr = x + (size_t)(row0 + wave) * CC;
    float v0 = xr[lane], v1 = xr[lane + 64], v2 = xr[lane + 128], v3 = xr[lane + 192];
    float s = v0 + v1 + v2 + v3;
    for (int off = 32; off; off >>= 1) s += __shfl_down(s, off);
    s = __shfl(s, 0);
    float mu = s * (1.0f / CC);
    float d0 = v0 - mu, d1 = v1 - mu, d2 = v2 - mu, d3 = v3 - mu;
    float vs = d0 * d0 + d1 * d1 + d2 * d2 + d3 * d3;
    for (int off = 32; off; off >>= 1) vs += __shfl_down(vs, off);
    vs = __shfl(vs, 0);
    float rstd = rsqrtf(vs * (1.0f / CC) + 1e-5f);
    xst[lane][wave]       = d0 * rstd * ln_g[lane]       + ln_b[lane];
    xst[lane + 64][wave]  = d1 * rstd * ln_g[lane + 64]  + ln_b[lane + 64];
    xst[lane + 128][wave] = d2 * rstd * ln_g[lane + 128] + ln_b[lane + 128];
    xst[lane + 192][wave] = d3 * rstd * ln_g[lane + 192] + ln_b[lane + 192];
    __syncthreads();
    // GEMM1: h[row0+r][t] = gelu(LN(x)@W_in + b_in)
    float a0 = b_in[t], a1 = a0, a2 = a0, a3 = a0;
    #pragma unroll 8
    for (int k = 0; k < CC; ++k) {
        float4 xv = *(const float4*)xst[k];     // uniform addr -> broadcast
        float wv = W_in[k * CC + t];
        a0 = fmaf(xv.x, wv, a0); a1 = fmaf(xv.y, wv, a1);
        a2 = fmaf(xv.z, wv, a2); a3 = fmaf(xv.w, wv, a3);
    }
    float h0 = gelu_fast(a0), h1 = gelu_fast(a1), h2 = gelu_fast(a2), h3 = gelu_fast(a3);
    float p0 = policy[row0], p1 = policy[row0 + 1], p2 = policy[row0 + 2], p3 = policy[row0 + 3];
    int b = row0 >> 10;
    if (t < HALF) {
        hst[t][0] = h0; hst[t][1] = h1; hst[t][2] = h2; hst[t][3] = h3;
    } else {
        atomicAdd(&gsum[b * HALF + (t - HALF)], h0 * p0 + h1 * p1 + h2 * p2 + h3 * p3);
    }
    if (t == 0) atomicAdd(&psum[b], p0 + p1 + p2 + p3);
    __syncthreads();
    // GEMM2: A[row0+r][t] = h_local[row0+r] @ W1[0:128]
    float c0 = 0, c1 = 0, c2 = 0, c3 = 0;
    #pragma unroll 8
    for (int k = 0; k < HALF; ++k) {
        float4 hv = *(const float4*)hst[k];     // uniform addr -> broadcast
        float wv = W1[k * CC + t];
        c0 = fmaf(hv.x, wv, c0); c1 = fmaf(hv.y, wv, c1);
        c2 = fmaf(hv.z, wv, c2); c3 = fmaf(hv.w, wv, c3);
    }
    int lr = row0 & (NN - 1);
    size_t tb = ((size_t)(b * 64 + (lr >> 4)) * 32 + (t >> 3)) * 128 + (t & 7);
    int r16 = lr & 15;
    At[tb + (r16 + 0) * 8] = c0;
    At[tb + (r16 + 1) * 8] = c1;
    At[tb + (r16 + 2) * 8] = c2;
    At[tb + (r16 + 3) * 8] = c3;
}

// ---- kB: blocks 0..199: Qc[b,i] = q@W1[256:512] + (b1 + glob@W1[128:256]);
//          blocks 200..231: W2 -> bf16 [n][k] transpose ----
__global__ __launch_bounds__(256) void kB_qc_prep(
        const float* __restrict__ query, const float* __restrict__ W1,
        const float* __restrict__ W2, const float* __restrict__ gsum,
        const float* __restrict__ psum, const float* __restrict__ b1,
        float* __restrict__ Qc, short* __restrict__ W2T) {
    int blk = blockIdx.x, t = threadIdx.x;
    if (blk < BB * NQ) {
        __shared__ float gl[HALF];
        __shared__ float qs[CC];
        int b = blk / NQ, i = blk % NQ;
        if (t < HALF) gl[t] = gsum[b * HALF + t] / psum[b];
        qs[t] = query[(size_t)(i * BB + b) * CC + t];
        __syncthreads();
        float g = b1[t];
        #pragma unroll 8
        for (int k = 0; k < HALF; ++k) g = fmaf(gl[k], W1[(HALF + k) * CC + t], g);
        #pragma unroll 8
        for (int k = 0; k < CC; ++k) g = fmaf(qs[k], W1[(2 * HALF + k) * CC + t], g);
        Qc[(size_t)blk * CC + t] = g;
    } else {
        int u = (blk - BB * NQ) * 256 + t;
        int c = u >> 6, kg = u & 63;
        short4 v;
        v.x = f2bf(W2[(kg * 4 + 0) * HALF + c]);
        v.y = f2bf(W2[(kg * 4 + 1) * HALF + c]);
        v.z = f2bf(W2[(kg * 4 + 2) * HALF + c]);
        v.w = f2bf(W2[(kg * 4 + 3) * HALF + c]);
        *(short4*)(W2T + c * CC + kg * 4) = v;
    }
}

// ---- k5: z1 frags in-register from tiled A -> MFMA vs LDS W2 -> gelu -> W3 -> lsm
// Block tile M=64, N=128; 4 waves, wave-tile m=16 x n=128 -> acc 32 AGPR.
// W2 staged in 4 chunks of K=64 (18.4 KB LDS) -> target 4+ blocks/CU.
#define W2S 72   // shorts: 144 B row stride, 9-word (odd) -> conflict-free-ish

__global__ __launch_bounds__(256, 4) void k5_main(
        const float* __restrict__ At, const float* __restrict__ Qc,
        const short* __restrict__ W2T, const float* __restrict__ b2,
        const float* __restrict__ W3, const float* __restrict__ b3,
        float* __restrict__ out) {
    __shared__ short w2s[128 * W2S];   // 18432 B

    int t = threadIdx.x;
    int lane = t & 63, w = t >> 6;
    int col16 = lane & 15, quad = lane >> 4;
    int blk = blockIdx.x;
    int jt = blk & 15;                 // 16 j-tiles; jt%8 spreads A slices over XCDs
    int iq = (blk >> 4) % NQ;
    int b  = blk / (16 * NQ);
    // wave w owns rows jt*64 + w*16 .. +15; lane row = +col16
    const float* Abase = At + ((size_t)(b * 64 + jt * 4 + w) * 32) * 128 + col16 * 8;
    const float* Qrow = Qc + (size_t)(b * NQ + iq) * CC;

    f32x4 acc[8];
    #pragma unroll
    for (int ni = 0; ni < 8; ++ni) acc[ni] = (f32x4){0.f, 0.f, 0.f, 0.f};

    for (int kt = 0; kt < 4; ++kt) {
        __syncthreads();
        #pragma unroll
        for (int e = 0; e < 4; ++e) {
            int u = e * 256 + t;
            int n = u >> 3, kg = u & 7;
            *(bf16x8*)&w2s[n * W2S + kg * 8] =
                *(const bf16x8*)(W2T + n * CC + kt * 64 + kg * 8);
        }
        __syncthreads();
        #pragma unroll
        for (int ks = 0; ks < 2; ++ks) {
            int k0 = kt * 64 + ks * 32 + quad * 8;
            float4 q0 = *(const float4*)(Qrow + k0);
            float4 q1 = *(const float4*)(Qrow + k0 + 4);
            const float* Ap = Abase + (size_t)(kt * 8 + ks * 4 + quad) * 128;
            float4 a0 = *(const float4*)(Ap);
            float4 a1 = *(const float4*)(Ap + 4);
            union { bf16x8 v; short s[8]; } u;
            u.s[0] = f2bf(gelu_fast(a0.x + q0.x));
            u.s[1] = f2bf(gelu_fast(a0.y + q0.y));
            u.s[2] = f2bf(gelu_fast(a0.z + q0.z));
            u.s[3] = f2bf(gelu_fast(a0.w + q0.w));
            u.s[4] = f2bf(gelu_fast(a1.x + q1.x));
            u.s[5] = f2bf(gelu_fast(a1.y + q1.y));
            u.s[6] = f2bf(gelu_fast(a1.z + q1.z));
            u.s[7] = f2bf(gelu_fast(a1.w + q1.w));
            int klocal = ks * 32 + quad * 8;
            #pragma unroll
            for (int ni = 0; ni < 8; ++ni) {
                bf16x8 bfv = *(const bf16x8*)&w2s[(ni * 16 + col16) * W2S + klocal];
                acc[ni] = __builtin_amdgcn_mfma_f32_16x16x32_bf16(u.v, bfv, acc[ni], 0, 0, 0);
            }
        }
    }

    // epilogue: z2 = gelu(acc + b2); logits = z2@W3; reduce over col16; lsm
    float p0[4] = {0, 0, 0, 0}, p1[4] = {0, 0, 0, 0};
    #pragma unroll
    for (int ni = 0; ni < 8; ++ni) {
        int c = ni * 16 + col16;
        float bb = b2[c];
        float2 w3v = *(const float2*)(W3 + c * 2);
        #pragma unroll
        for (int r = 0; r < 4; ++r) {
            float z = gelu_fast(acc[ni][r] + bb);
            p0[r] = fmaf(z, w3v.x, p0[r]);
            p1[r] = fmaf(z, w3v.y, p1[r]);
        }
    }
    float b30 = b3[0], b31 = b3[1];
    #pragma unroll
    for (int r = 0; r < 4; ++r) {
        float s0 = p0[r], s1 = p1[r];
        #pragma unroll
        for (int off = 1; off < 16; off <<= 1) {
            s0 += __shfl_xor(s0, off);
            s1 += __shfl_xor(s1, off);
        }
        if (col16 == 0) {
            float z0 = s0 + b30, z1v = s1 + b31;
            float m = fmaxf(z0, z1v);
            float lse = m + __logf(__expf(z0 - m) + __expf(z1v - m));
            int j = jt * 64 + w * 16 + quad * 4 + r;
            *(float2*)(out + ((size_t)(b * NQ + iq) * NN + j) * 2) =
                make_float2(z0 - lse, z1v - lse);
        }
    }
}

extern "C" void kernel_launch(void* const* d_in, const int* in_sizes, int n_in,
                              void* d_out, int out_size, void* d_ws, size_t ws_size,
                              hipStream_t stream) {
    const float* x      = (const float*)d_in[0];
    const float* query  = (const float*)d_in[1];
    const float* policy = (const float*)d_in[2];
    const float* ln_g   = (const float*)d_in[3];
    const float* ln_b   = (const float*)d_in[4];
    const float* W_in   = (const float*)d_in[5];
    const float* b_in   = (const float*)d_in[6];
    const float* W1     = (const float*)d_in[7];
    const float* b1     = (const float*)d_in[8];
    const float* W2     = (const float*)d_in[9];
    const float* b2     = (const float*)d_in[10];
    const float* W3     = (const float*)d_in[11];
    const float* b3     = (const float*)d_in[12];
    float* out = (float*)d_out;

    float* ws    = (float*)d_ws;
    float* At    = ws;                 // 2*1024*256 fp32 (tiled)
    float* Qc    = ws + 524288;        // 200*256
    float* gsum  = ws + 575488;        // 2*128
    float* psum  = ws + 575744;        // 2
    short* W2T   = (short*)(ws + 575746 + 62);  // 128*256 bf16, 16B-aligned region

    hipMemsetAsync(gsum, 0, (2 * HALF + 2) * sizeof(float), stream);
    kA_fused<<<(BB * NN) / 4, 256, 0, stream>>>(x, ln_g, ln_b, W_in, b_in, policy,
                                                W1, At, gsum, psum);
    kB_qc_prep<<<BB * NQ + 32, 256, 0, stream>>>(query, W1, W2, gsum, psum, b1, Qc, W2T);
    k5_main<<<BB * NQ * (NN / 64), 256, 0, stream>>>(At, Qc, W2T, b2, W3, b3, out);
}